// Round 6
// baseline (124.359 us; speedup 1.0000x reference)
//
#include <hip/hip_runtime.h>
#include <hip/hip_bf16.h>

typedef __bf16 bf16;
typedef __attribute__((ext_vector_type(8))) __bf16 bf16x8;
typedef __attribute__((ext_vector_type(4))) float f32x4;
typedef __attribute__((ext_vector_type(4))) int i32x4;

#define CH 192
#define MAT (CH * CH)            // 36864
#define NF 145                   // canonical frequencies of 17x17 grid (conj symmetry)
#define NELEM (CH * CH * 9)      // 331776
#define XSCALE 9.765625e-4f      // 2^-10, exact; sigma = 1024*(s3/289)^(1/16)
#define W17 0.36959913571644626f // 2*pi/17

// ---------------------------------------------------------------------------
// sigma = ||G^3(K)||_F^(1/8) via 17x17 spectral sampling (exact Parseval).
// ROUND-11 CHANGE (kill the X intermediate): r5 counters showed X costing
// 3 ways: k_dft writes 21.4 MB, k_g3 re-fetches 22.4 MB from HBM (L2 did not
// retain), and 23.8 MB dirty-writeback lands inside k_g3's window. The DFT is
// ~20 FMA/entry -> recompute it INSIDE k_g3's staging phase (per-freq DFT of
// K into swizzled LDS, ~2.5 us VALU). Enabler: k_tr pre-transposes K ->
// Kt[a][o][9] f32 (1.3 MB, shared by all blocks, L2/L3-hot) so staging reads
// are 288-B contiguous per lane. Removes k_dft dispatch + X round-trip + gap.
// Also: MFMA order interleaved cr,ci,cr,ci (per-accumulator order unchanged
// -> bitwise identical; no back-to-back dependent MFMA).
// Lessons pinned:
//  - wave reg budget = 512/(waves/SIMD); 16-wave block -> 128/wave. Accums
//    must fit or scratch eats 100 us (r2-r4). r5 config (waves_per_eu(4,4),
//    global-side... now LDS-side swizzle, 48x48/wave) is spill-free: KEEP.
//  - XOR chunk swizzle c'=(c&~7)|((c&7)^(r&7)) BOTH sides (write + read):
//    bank conflicts 2.0M -> 0 (r5). Staging ds_writes use the same swizzle.
//  - staging/epilogue FULLY UNROLLED, compile-time indices.
//  - k_scale fusion via spinner regressed (old r6). Keep separate dispatch.
//  - harness ws fill (~44 us) is inside the timed window: floor = 44 + work.
// ws layout: [0] float s3; [256] Kt f32 [a][o][9] (1.3 MB).
// ---------------------------------------------------------------------------

__device__ __forceinline__ int swz8(int c, int r) {
    return (c & ~7) | ((c & 7) ^ (r & 7));       // 16-B chunk XOR swizzle
}

// Kt[(a*CH+o)*9+i] = K[(o*CH+a)*9+i]; also zero s3 (stream-ordered).
__global__ void k_tr(const float* __restrict__ K, float* __restrict__ Kt,
                     float* __restrict__ s3) {
    int p = blockIdx.x * 256 + threadIdx.x;      // 144 blocks = 36864 pairs
    if (p == 0) *s3 = 0.0f;
    int a = p / CH, o = p % CH;
    const float* src = K + ((size_t)o * CH + a) * 9;
    float* dst = Kt + (size_t)p * 9;
#pragma unroll
    for (int i = 0; i < 9; ++i) dst[i] = src[i];
}

// ---------------------------------------------------------------------------
// k_g3: per-frequency fused DFT + triple gram. One block = one freq, 1024 thr.
// Staging: each thread DFTs 4-5 chunks (8 entries each) of X_f straight into
// swizzled LDS (Re/Im slabs [192][192] bf16, 147456 B). Then 3 gram rounds:
// 16 waves, wave w owns ONE 48x48 tile (rows (w>>2)*48, cols (w&3)*48);
// MFMA from LDS -> barrier -> accum->bf16 swizzled write-back -> barrier.
// Final round: Frobenius norm of accums -> atomic add to s3.
// ---------------------------------------------------------------------------
#define KVE(j, i) kv4[((j) * 9 + (i)) >> 2][((j) * 9 + (i)) & 3]

__global__ __launch_bounds__(1024, 4)
__attribute__((amdgpu_waves_per_eu(4, 4)))
void k_g3(const float* __restrict__ Kt, float* __restrict__ s3) {
    __shared__ __align__(16) bf16 lds[2 * MAT];   // 147456 B
    __shared__ float twc[17], tws[17];
    __shared__ float red[16];
    int f = blockIdx.x;                 // 145 blocks
    int tid = threadIdx.x;
    int lane = tid & 63, w = tid >> 6;
    int ml = lane & 15, kqc = lane >> 4;
    int rb = (w >> 2) * 48;             // row band
    int cb = (w & 3) * 48;              // col band

    if (tid < 17) {
        float s, c;
        __sincosf(-W17 * (float)tid, &s, &c);
        twc[tid] = c; tws[tid] = s;
    }
    __syncthreads();

    // ---- per-freq twiddles (block-uniform; same expressions as old k_dft) --
    int fy, fx;
    if (f < 9) { fy = 0; fx = f; }
    else { int uu = f - 9; fy = 1 + uu / 17; fx = uu % 17; }
    float pyr = twc[fy], pyi = tws[fy];
    float pxr = twc[fx], pxi = tws[fx];
    int fx2 = 2 * fx; if (fx2 >= 17) fx2 -= 17;
    int fy2 = 2 * fy; if (fy2 >= 17) fy2 -= 17;
    float px2r = twc[fx2], px2i = tws[fx2];
    float py2r = twc[fy2], py2i = tws[fy2];

    // ---- stage: DFT K -> X_f directly into swizzled LDS (4608 chunks) ----
#pragma unroll
    for (int j5 = 0; j5 < 5; ++j5) {
        int cidx = j5 * 1024 + tid;
        if (cidx < 4608) {                        // last pass: waves 0-7 only
            int a = cidx / 24, c = cidx % 24;
            int o0 = c * 8;
            const float* src = Kt + ((size_t)a * CH + o0) * 9;  // 288-B aligned
            f32x4 kv4[18];
#pragma unroll
            for (int i = 0; i < 18; ++i) kv4[i] = *(const f32x4*)(src + i * 4);
            bf16x8 vr, vi;
#pragma unroll
            for (int j = 0; j < 8; ++j) {
                // row sums s_y = k[y0] + k[y1]*px + k[y2]*px^2  (k real)
                float s0r = KVE(j,0) + KVE(j,1) * pxr + KVE(j,2) * px2r;
                float s0i = KVE(j,1) * pxi + KVE(j,2) * px2i;
                float s1r = KVE(j,3) + KVE(j,4) * pxr + KVE(j,5) * px2r;
                float s1i = KVE(j,4) * pxi + KVE(j,5) * px2i;
                float s2r = KVE(j,6) + KVE(j,7) * pxr + KVE(j,8) * px2r;
                float s2i = KVE(j,7) * pxi + KVE(j,8) * px2i;
                float ar = s0r + pyr * s1r - pyi * s1i + py2r * s2r - py2i * s2i;
                float ai = s0i + pyr * s1i + pyi * s1r + py2r * s2i + py2i * s2r;
                vr[j] = (bf16)(ar * XSCALE);
                vi[j] = (bf16)(ai * XSCALE);
            }
            int e = a * CH + swz8(c, a) * 8;      // swizzled (write side)
            *(i32x4*)&lds[e]       = __builtin_bit_cast(i32x4, vr);
            *(i32x4*)&lds[MAT + e] = __builtin_bit_cast(i32x4, vi);
        }
    }
    __syncthreads();

    // per-thread frag row constants
    int arow[3], abit[3], brow[3], bbit[3];
#pragma unroll
    for (int i = 0; i < 3; ++i) {
        int ra = rb + i * 16 + ml;
        arow[i] = ra * CH; abit[i] = ra & 7;
        int rc = cb + i * 16 + ml;
        brow[i] = rc * CH; bbit[i] = rc & 7;
    }

    f32x4 cr[3][3], ci[3][3];
#pragma unroll 1
    for (int round = 0; round < 3; ++round) {
#pragma unroll
        for (int i = 0; i < 3; ++i)
#pragma unroll
            for (int j = 0; j < 3; ++j) {
                cr[i][j] = f32x4{0.f, 0.f, 0.f, 0.f};
                ci[i][j] = f32x4{0.f, 0.f, 0.f, 0.f};
            }
#pragma unroll
        for (int ks8 = 0; ks8 < 24; ks8 += 4) {     // K step 32 = 4 chunks
            int c0 = ks8 + kqc;
            bf16x8 ar[3], ai[3];
#pragma unroll
            for (int mt = 0; mt < 3; ++mt) {
                int e = arow[mt] + swz8(c0, abit[mt]) * 8;
                ar[mt] = *(const bf16x8*)&lds[e];
                ai[mt] = *(const bf16x8*)&lds[MAT + e];
            }
#pragma unroll
            for (int nt = 0; nt < 3; ++nt) {
                int e = brow[nt] + swz8(c0, bbit[nt]) * 8;
                bf16x8 br = *(const bf16x8*)&lds[e];
                bf16x8 bi = *(const bf16x8*)&lds[MAT + e];
                i32x4 u = __builtin_bit_cast(i32x4, br);
                u ^= 0x80008000;                    // nbr = -br (8 bf16)
                bf16x8 nbr = __builtin_bit_cast(bf16x8, u);
#pragma unroll
                for (int mt = 0; mt < 3; ++mt) {
                    // cr += ar*br + ai*bi ; ci += ar*bi + ai*(-br)
                    // interleaved cr,ci,cr,ci: per-accum order unchanged
                    cr[mt][nt] = __builtin_amdgcn_mfma_f32_16x16x32_bf16(ar[mt], br,  cr[mt][nt], 0, 0, 0);
                    ci[mt][nt] = __builtin_amdgcn_mfma_f32_16x16x32_bf16(ar[mt], bi,  ci[mt][nt], 0, 0, 0);
                    cr[mt][nt] = __builtin_amdgcn_mfma_f32_16x16x32_bf16(ai[mt], bi,  cr[mt][nt], 0, 0, 0);
                    ci[mt][nt] = __builtin_amdgcn_mfma_f32_16x16x32_bf16(ai[mt], nbr, ci[mt][nt], 0, 0, 0);
                }
            }
        }
        if (round < 2) {
            __syncthreads();                        // all LDS reads done
            int lr = kqc * 4;
#pragma unroll
            for (int mt = 0; mt < 3; ++mt)
#pragma unroll
                for (int nt = 0; nt < 3; ++nt)
#pragma unroll
                    for (int rr = 0; rr < 4; ++rr) {
                        int row = rb + mt * 16 + lr + rr;
                        int col = cb + nt * 16 + ml;
                        int e = row * CH + swz8(col >> 3, row) * 8 + (col & 7);
                        lds[e]       = (bf16)cr[mt][nt][rr];
                        lds[MAT + e] = (bf16)ci[mt][nt][rr];
                    }
            __syncthreads();                        // writes visible to round+1
        }
    }

    // ---- Frobenius norm of round-3 accums (full matrix, weight 1/tile) ----
    float loc = 0.f;
#pragma unroll
    for (int mt = 0; mt < 3; ++mt)
#pragma unroll
        for (int nt = 0; nt < 3; ++nt)
#pragma unroll
            for (int rr = 0; rr < 4; ++rr)
                loc += cr[mt][nt][rr] * cr[mt][nt][rr] + ci[mt][nt][rr] * ci[mt][nt][rr];
#pragma unroll
    for (int off = 32; off > 0; off >>= 1) loc += __shfl_down(loc, off, 64);
    if (lane == 0) red[w] = loc;
    __syncthreads();
    if (tid == 0) {
        float base = (f == 0) ? 1.0f : 2.0f;        // conj-pair weight over freqs
        float acc = 0.f;
#pragma unroll
        for (int i = 0; i < 16; ++i) acc += red[i];
        atomicAdd(s3, base * acc);
    }
}

// sigma = 1024 * (s3/289)^(1/16);  out = K / sigma
__global__ void k_scale(const float* __restrict__ K, float* __restrict__ out,
                        const float* __restrict__ s3) {
    float sig = 1024.0f * exp2f(log2f((*s3) * (1.0f / 289.0f)) * 0.0625f);
    float inv = 1.0f / sig;
    int i = (blockIdx.x * 256 + threadIdx.x) * 4;   // 324 blocks exact
    f32x4 v = *(const f32x4*)(K + i);
    v *= inv;
    *(f32x4*)(out + i) = v;
}

extern "C" void kernel_launch(void* const* d_in, const int* in_sizes, int n_in,
                              void* d_out, int out_size, void* d_ws, size_t ws_size,
                              hipStream_t stream) {
    const float* K = (const float*)d_in[0];
    float* out = (float*)d_out;
    char* ws = (char*)d_ws;
    float* s3 = (float*)ws;
    float* Kt = (float*)(ws + 256);

    k_tr<<<NELEM / (256 * 9), 256, 0, stream>>>(K, Kt, s3);   // Kt (1.3 MB) + s3=0
    k_g3<<<NF, 1024, 0, stream>>>(Kt, s3);                    // DFT + 3 gram rounds
    k_scale<<<NELEM / 1024, 256, 0, stream>>>(K, out, s3);    // out = K/sigma
}

// Round 7
// 120.094 us; speedup vs baseline: 1.0355x; 1.0355x over previous
//
#include <hip/hip_runtime.h>
#include <hip/hip_bf16.h>

typedef __bf16 bf16;
typedef __attribute__((ext_vector_type(8))) __bf16 bf16x8;
typedef __attribute__((ext_vector_type(4))) __bf16 bf16x4;
typedef __attribute__((ext_vector_type(4))) float f32x4;
typedef __attribute__((ext_vector_type(4))) int i32x4;
typedef __attribute__((ext_vector_type(2))) int i32x2;

#define CH 192
#define MAT (CH * CH)            // 36864
#define NF 145                   // canonical frequencies of 17x17 grid (conj symmetry)
#define NELEM (CH * CH * 9)      // 331776
#define XSCALE 9.765625e-4f      // 2^-10, exact; sigma = 1024*(s3/289)^(1/16)
#define W17 0.36959913571644626f // 2*pi/17

// ---------------------------------------------------------------------------
// sigma = ||G^3(K)||_F^(1/8) via 17x17 spectral sampling (exact Parseval).
// ROUND-12 CHANGE (fix r6's staging spill): r6 fully unrolled the 5-iter
// staging loop, each iter holding kv4[18]=72 VGPRs -> loads hoisted across
// iterations -> scratch (WRITE_SIZE 19 MB on an atomic-only kernel, dur +25us).
// Fixes:
//  - j5 loop is '#pragma unroll 1' (iterations self-contained, no carried
//    arrays); entries processed as 2 half-groups of 4 with SCALAR 9-float
//    loads (live ~40-55 regs) + ds_write_b64 per group; sched_barrier(0)
//    between groups/iters stops load batching.
//  - k_tr: coalesced READ of K (thread p reads K+9p), scattered 36-B writes.
//  - s_setprio(1/0) around the MFMA cluster (T5; no semantic change).
// Round loop: UNCHANGED from r5 (proven 52 us, spill-free, 0 bank conflicts).
// Lessons pinned:
//  - 16-wave block: compiler insists on ~64 arch VGPRs (+accums in AGPRs);
//    ANY phase needing >64 live VGPRs spills. waves_per_eu(4,4) did NOT
//    raise it (r5/r6: VGPR_Count=64 both). Keep every phase's live set small.
//  - 8-wave blocks cap at 128 VGPRs (r2/r3) -> 144-accum tilings spill. Do
//    NOT restructure to 96x48/wave without solving this.
//  - XOR chunk swizzle c'=(c&~7)|((c&7)^(r&7)) BOTH sides: conflicts 2M -> 0.
//  - k_scale fusion via spinner regressed (old r6). Keep separate dispatch.
//  - harness ws fill (~44 us) is inside the timed window: floor = 44 + work.
// ws layout: [0] float s3; [256] Kt f32 [a][o][9] (1.3 MB).
// ---------------------------------------------------------------------------

__device__ __forceinline__ int swz8(int c, int r) {
    return (c & ~7) | ((c & 7) ^ (r & 7));       // 16-B chunk XOR swizzle
}

// Kt[(a*CH+o)*9+i] = K[(o*CH+a)*9+i]; coalesced read, scattered write.
// Also zeroes s3 (stream-ordered before k_g3's atomics).
__global__ void k_tr(const float* __restrict__ K, float* __restrict__ Kt,
                     float* __restrict__ s3) {
    int p = blockIdx.x * 256 + threadIdx.x;      // 144 blocks = 36864 rows
    if (p == 0) *s3 = 0.0f;
    int o = p / CH, a = p % CH;                  // read side is linear in p
    const float* src = K + (size_t)p * 9;
    float* dst = Kt + ((size_t)a * CH + o) * 9;
#pragma unroll
    for (int i = 0; i < 9; ++i) dst[i] = src[i];
}

// ---------------------------------------------------------------------------
// k_g3: per-frequency fused DFT + triple gram. One block = one freq, 1024 thr.
// Staging: each thread DFTs 4-5 chunks (8 entries, two half-groups of 4) of
// X_f straight into swizzled LDS (Re/Im slabs [192][192] bf16, 147456 B).
// Then 3 gram rounds: 16 waves, wave w owns ONE 48x48 tile (rows (w>>2)*48,
// cols (w&3)*48); MFMA from LDS -> barrier -> accum->bf16 swizzled
// write-back -> barrier. Final: Frobenius norm of accums -> atomic.
// ---------------------------------------------------------------------------
__global__ __launch_bounds__(1024, 4)
__attribute__((amdgpu_waves_per_eu(4, 4)))
void k_g3(const float* __restrict__ Kt, float* __restrict__ s3) {
    __shared__ __align__(16) bf16 lds[2 * MAT];   // 147456 B
    __shared__ float twc[17], tws[17];
    __shared__ float red[16];
    int f = blockIdx.x;                 // 145 blocks
    int tid = threadIdx.x;
    int lane = tid & 63, w = tid >> 6;
    int ml = lane & 15, kqc = lane >> 4;
    int rb = (w >> 2) * 48;             // row band
    int cb = (w & 3) * 48;              // col band

    if (tid < 17) {
        float s, c;
        __sincosf(-W17 * (float)tid, &s, &c);
        twc[tid] = c; tws[tid] = s;
    }
    __syncthreads();

    // ---- per-freq twiddles (block-uniform; same expressions as old k_dft) --
    int fy, fx;
    if (f < 9) { fy = 0; fx = f; }
    else { int uu = f - 9; fy = 1 + uu / 17; fx = uu % 17; }
    float pyr = twc[fy], pyi = tws[fy];
    float pxr = twc[fx], pxi = tws[fx];
    int fx2 = 2 * fx; if (fx2 >= 17) fx2 -= 17;
    int fy2 = 2 * fy; if (fy2 >= 17) fy2 -= 17;
    float px2r = twc[fx2], px2i = tws[fx2];
    float py2r = twc[fy2], py2i = tws[fy2];

    // ---- stage: DFT K -> X_f into swizzled LDS (4608 chunks of 8) ----
    // Small live set: per half-group of 4 entries, 9 scalar loads each.
#pragma unroll 1
    for (int j5 = 0; j5 < 5; ++j5) {
        int cidx = j5 * 1024 + tid;
        if (cidx < 4608) {                        // last pass: waves 0-7 only
            int a = cidx / 24, c = cidx % 24;
            int o0 = c * 8;
            const float* src = Kt + ((size_t)a * CH + o0) * 9;
            int e = a * CH + swz8(c, a) * 8;      // swizzled chunk base
#pragma unroll
            for (int g = 0; g < 2; ++g) {
                bf16x4 vr4, vi4;
#pragma unroll
                for (int j = 0; j < 4; ++j) {
                    const float* kp = src + (g * 4 + j) * 9;
                    float k0 = kp[0], k1 = kp[1], k2 = kp[2];
                    float k3 = kp[3], k4 = kp[4], k5 = kp[5];
                    float k6 = kp[6], k7 = kp[7], k8 = kp[8];
                    // row sums s_y = k[y0] + k[y1]*px + k[y2]*px^2 (k real)
                    float s0r = k0 + k1 * pxr + k2 * px2r, s0i = k1 * pxi + k2 * px2i;
                    float s1r = k3 + k4 * pxr + k5 * px2r, s1i = k4 * pxi + k5 * px2i;
                    float s2r = k6 + k7 * pxr + k8 * px2r, s2i = k7 * pxi + k8 * px2i;
                    float ar = s0r + pyr * s1r - pyi * s1i + py2r * s2r - py2i * s2i;
                    float ai = s0i + pyr * s1i + pyi * s1r + py2r * s2i + py2i * s2r;
                    vr4[j] = (bf16)(ar * XSCALE);
                    vi4[j] = (bf16)(ai * XSCALE);
                }
                *(i32x2*)&lds[e + g * 4]       = __builtin_bit_cast(i32x2, vr4);
                *(i32x2*)&lds[MAT + e + g * 4] = __builtin_bit_cast(i32x2, vi4);
                __builtin_amdgcn_sched_barrier(0);   // no cross-group batching
            }
        }
        __builtin_amdgcn_sched_barrier(0);           // no cross-iter batching
    }
    __syncthreads();

    // per-thread frag row constants
    int arow[3], abit[3], brow[3], bbit[3];
#pragma unroll
    for (int i = 0; i < 3; ++i) {
        int ra = rb + i * 16 + ml;
        arow[i] = ra * CH; abit[i] = ra & 7;
        int rc = cb + i * 16 + ml;
        brow[i] = rc * CH; bbit[i] = rc & 7;
    }

    f32x4 cr[3][3], ci[3][3];
#pragma unroll 1
    for (int round = 0; round < 3; ++round) {
#pragma unroll
        for (int i = 0; i < 3; ++i)
#pragma unroll
            for (int j = 0; j < 3; ++j) {
                cr[i][j] = f32x4{0.f, 0.f, 0.f, 0.f};
                ci[i][j] = f32x4{0.f, 0.f, 0.f, 0.f};
            }
#pragma unroll
        for (int ks8 = 0; ks8 < 24; ks8 += 4) {     // K step 32 = 4 chunks
            int c0 = ks8 + kqc;
            bf16x8 ar[3], ai[3];
#pragma unroll
            for (int mt = 0; mt < 3; ++mt) {
                int e = arow[mt] + swz8(c0, abit[mt]) * 8;
                ar[mt] = *(const bf16x8*)&lds[e];
                ai[mt] = *(const bf16x8*)&lds[MAT + e];
            }
#pragma unroll
            for (int nt = 0; nt < 3; ++nt) {
                int e = brow[nt] + swz8(c0, bbit[nt]) * 8;
                bf16x8 br = *(const bf16x8*)&lds[e];
                bf16x8 bi = *(const bf16x8*)&lds[MAT + e];
                i32x4 u = __builtin_bit_cast(i32x4, br);
                u ^= 0x80008000;                    // nbr = -br (8 bf16)
                bf16x8 nbr = __builtin_bit_cast(bf16x8, u);
                __builtin_amdgcn_s_setprio(1);      // favor MFMA-entering wave
#pragma unroll
                for (int mt = 0; mt < 3; ++mt) {
                    // cr += ar*br + ai*bi ; ci += ar*bi + ai*(-br)
                    // interleaved cr,ci,cr,ci: per-accum order unchanged
                    cr[mt][nt] = __builtin_amdgcn_mfma_f32_16x16x32_bf16(ar[mt], br,  cr[mt][nt], 0, 0, 0);
                    ci[mt][nt] = __builtin_amdgcn_mfma_f32_16x16x32_bf16(ar[mt], bi,  ci[mt][nt], 0, 0, 0);
                    cr[mt][nt] = __builtin_amdgcn_mfma_f32_16x16x32_bf16(ai[mt], bi,  cr[mt][nt], 0, 0, 0);
                    ci[mt][nt] = __builtin_amdgcn_mfma_f32_16x16x32_bf16(ai[mt], nbr, ci[mt][nt], 0, 0, 0);
                }
                __builtin_amdgcn_s_setprio(0);
            }
        }
        if (round < 2) {
            __syncthreads();                        // all LDS reads done
            int lr = kqc * 4;
#pragma unroll
            for (int mt = 0; mt < 3; ++mt)
#pragma unroll
                for (int nt = 0; nt < 3; ++nt)
#pragma unroll
                    for (int rr = 0; rr < 4; ++rr) {
                        int row = rb + mt * 16 + lr + rr;
                        int col = cb + nt * 16 + ml;
                        int e = row * CH + swz8(col >> 3, row) * 8 + (col & 7);
                        lds[e]       = (bf16)cr[mt][nt][rr];
                        lds[MAT + e] = (bf16)ci[mt][nt][rr];
                    }
            __syncthreads();                        // writes visible to round+1
        }
    }

    // ---- Frobenius norm of round-3 accums (full matrix, weight 1/tile) ----
    float loc = 0.f;
#pragma unroll
    for (int mt = 0; mt < 3; ++mt)
#pragma unroll
        for (int nt = 0; nt < 3; ++nt)
#pragma unroll
            for (int rr = 0; rr < 4; ++rr)
                loc += cr[mt][nt][rr] * cr[mt][nt][rr] + ci[mt][nt][rr] * ci[mt][nt][rr];
#pragma unroll
    for (int off = 32; off > 0; off >>= 1) loc += __shfl_down(loc, off, 64);
    if (lane == 0) red[w] = loc;
    __syncthreads();
    if (tid == 0) {
        float base = (f == 0) ? 1.0f : 2.0f;        // conj-pair weight over freqs
        float acc = 0.f;
#pragma unroll
        for (int i = 0; i < 16; ++i) acc += red[i];
        atomicAdd(s3, base * acc);
    }
}

// sigma = 1024 * (s3/289)^(1/16);  out = K / sigma
__global__ void k_scale(const float* __restrict__ K, float* __restrict__ out,
                        const float* __restrict__ s3) {
    float sig = 1024.0f * exp2f(log2f((*s3) * (1.0f / 289.0f)) * 0.0625f);
    float inv = 1.0f / sig;
    int i = (blockIdx.x * 256 + threadIdx.x) * 4;   // 324 blocks exact
    f32x4 v = *(const f32x4*)(K + i);
    v *= inv;
    *(f32x4*)(out + i) = v;
}

extern "C" void kernel_launch(void* const* d_in, const int* in_sizes, int n_in,
                              void* d_out, int out_size, void* d_ws, size_t ws_size,
                              hipStream_t stream) {
    const float* K = (const float*)d_in[0];
    float* out = (float*)d_out;
    char* ws = (char*)d_ws;
    float* s3 = (float*)ws;
    float* Kt = (float*)(ws + 256);

    k_tr<<<NELEM / (256 * 9), 256, 0, stream>>>(K, Kt, s3);   // Kt (1.3 MB) + s3=0
    k_g3<<<NF, 1024, 0, stream>>>(Kt, s3);                    // DFT + 3 gram rounds
    k_scale<<<NELEM / 1024, 256, 0, stream>>>(K, out, s3);    // out = K/sigma
}

// Round 8
// 108.192 us; speedup vs baseline: 1.1494x; 1.1100x over previous
//
#include <hip/hip_runtime.h>
#include <hip/hip_bf16.h>

typedef __bf16 bf16;
typedef __attribute__((ext_vector_type(8))) __bf16 bf16x8;
typedef __attribute__((ext_vector_type(4))) __bf16 bf16x4;
typedef __attribute__((ext_vector_type(4))) float f32x4;
typedef __attribute__((ext_vector_type(4))) int i32x4;
typedef __attribute__((ext_vector_type(2))) int i32x2;

#define CH 192
#define MAT (CH * CH)            // 36864
#define NF 145                   // canonical frequencies of 17x17 grid (conj symmetry)
#define NELEM (CH * CH * 9)      // 331776
#define XSCALE 9.765625e-4f      // 2^-10, exact; sigma = 1024*(s3/289)^(1/16)
#define W17 0.36959913571644626f // 2*pi/17

// ---------------------------------------------------------------------------
// sigma = ||G^3(K)||_F^(1/8) via 17x17 spectral sampling (exact Parseval).
// ROUND-13 CHANGES (fix r7's gather-bound staging + shrink rounds):
//  - r7 post-mortem: staging read Kt rows at 288-B lane stride -> every
//    scalar load gathered 64 cache lines (~324/thread, TA-issue-bound,
//    sched_barrier-serialized) => +22 us vs r5's coalesced staging.
//  - DFT refactored to 9-PLANE form: X_f = sum_i c_i * K_i, c_i = py^y px^x
//    * 2^-10 block-uniform. k_tr emits planes Kt[i][a][o] (1.33 MB); staging
//    reads 2x f32x4 per plane chunk (fully coalesced), 16 f32 accum regs,
//    live ~45 -> no spill, no gather.
//  - TRANSPOSED-PACKED write-back: store H^T; lane's 4 rr-rows become 4
//    consecutive elems -> 18 ds_write_b64 vs 72 ds_write_b16. Computed gram
//    is bitwise-Hermitian (conj is sign-only, f32 rounding sign-symmetric),
//    so the transposes cancel (S2 = H2 exactly); s3 unchanged.
//  - TRIANGLE round 3: norm-only, |H3[m,n]|=|H3[n,m]| bitwise -> 10/16
//    tiles, off-diag weight 2.
// Lessons pinned:
//  - 16-wave block: ~64 arch VGPR + accums in AGPR (4 waves/SIMD x 128).
//    Any phase >64 live arch VGPRs spills (r2-r6). Keep live sets small.
//  - Lane-adjacent addresses MUST be contiguous; per-lane-contiguous rows
//    with 288-B lane stride = 64-line gather per instr (r7).
//  - XOR chunk swizzle c'=(c&~7)|((c&7)^(r&7)) BOTH sides: conflicts 2M->0.
//  - k_scale fusion via spinner regressed (old session). Separate dispatch.
//  - harness ws fill (~44 us) is inside the timed window: floor = 44 + work.
// ws layout: [0] float s3; [256] Kt f32 [i][a][o] 9 planes (1.33 MB).
// ---------------------------------------------------------------------------

__device__ __forceinline__ int swz8(int c, int r) {
    return (c & ~7) | ((c & 7) ^ (r & 7));       // 16-B chunk XOR swizzle
}

// Kt[i*MAT + a*CH + o] = K[(o*CH+a)*9 + i]; coalesced 36-B read per thread,
// 9 scattered scalar writes (fire-and-forget). Also zeroes s3.
__global__ void k_tr(const float* __restrict__ K, float* __restrict__ Kt,
                     float* __restrict__ s3) {
    int p = blockIdx.x * 256 + threadIdx.x;      // 144 blocks = 36864 rows
    if (p == 0) *s3 = 0.0f;
    int o = p / CH, a = p % CH;
    const float* src = K + (size_t)p * 9;
#pragma unroll
    for (int i = 0; i < 9; ++i)
        Kt[(size_t)i * MAT + a * CH + o] = src[i];
}

// ---------------------------------------------------------------------------
// k_g3: per-frequency fused DFT + triple gram. One block = one freq, 1024 thr.
// Staging: 9-plane coeff DFT, coalesced f32x4 plane reads -> swizzled LDS
// (Re/Im slabs [192][192] bf16, 147456 B). 3 gram rounds: 16 waves, wave w
// owns ONE 48x48 tile (rows (w>>2)*48, cols (w&3)*48); MFMA from LDS ->
// barrier -> transposed-packed b64 write-back -> barrier. Round 3: upper
// triangle only, Frobenius norm of accums (off-diag x2) -> atomic.
// ---------------------------------------------------------------------------
__global__ __launch_bounds__(1024, 4)
__attribute__((amdgpu_waves_per_eu(4, 4)))
void k_g3(const float* __restrict__ Kt, float* __restrict__ s3) {
    __shared__ __align__(16) bf16 lds[2 * MAT];   // 147456 B
    __shared__ float twc[17], tws[17];
    __shared__ float red[16];
    int f = blockIdx.x;                 // 145 blocks
    int tid = threadIdx.x;
    int lane = tid & 63, w = tid >> 6;
    int ml = lane & 15, kqc = lane >> 4;
    int rb = (w >> 2) * 48;             // row band
    int cb = (w & 3) * 48;              // col band

    if (tid < 17) {
        float s, c;
        __sincosf(-W17 * (float)tid, &s, &c);
        twc[tid] = c; tws[tid] = s;
    }
    __syncthreads();

    // ---- 9 block-uniform complex coeffs c[y*3+x] = py^y * px^x * 2^-10 ----
    int fy, fx;
    if (f < 9) { fy = 0; fx = f; }
    else { int uu = f - 9; fy = 1 + uu / 17; fx = uu % 17; }
    float pyr = twc[fy], pyi = tws[fy];
    float pxr = twc[fx], pxi = tws[fx];
    int fx2 = 2 * fx; if (fx2 >= 17) fx2 -= 17;
    int fy2 = 2 * fy; if (fy2 >= 17) fy2 -= 17;
    float px2r = twc[fx2], px2i = tws[fx2];
    float py2r = twc[fy2], py2i = tws[fy2];
    float cR[9], cI[9];
    cR[0] = 1.0f;  cI[0] = 0.0f;
    cR[1] = pxr;   cI[1] = pxi;
    cR[2] = px2r;  cI[2] = px2i;
    cR[3] = pyr;   cI[3] = pyi;
    cR[4] = pyr * pxr - pyi * pxi;    cI[4] = pyr * pxi + pyi * pxr;
    cR[5] = pyr * px2r - pyi * px2i;  cI[5] = pyr * px2i + pyi * px2r;
    cR[6] = py2r;  cI[6] = py2i;
    cR[7] = py2r * pxr - py2i * pxi;  cI[7] = py2r * pxi + py2i * pxr;
    cR[8] = py2r * px2r - py2i * px2i; cI[8] = py2r * px2i + py2i * px2r;
#pragma unroll
    for (int i = 0; i < 9; ++i) { cR[i] *= XSCALE; cI[i] *= XSCALE; }  // exact 2^-10

    // ---- stage: X_f = sum_i c_i * plane_i -> swizzled LDS (4608 chunks) ----
#pragma unroll 1
    for (int j5 = 0; j5 < 5; ++j5) {
        int cidx = j5 * 1024 + tid;
        if (cidx < 4608) {                        // last pass: waves 0-7 only
            int a = cidx / 24, c = cidx % 24;
            const float* base = Kt + a * CH + c * 8;
            float xr0 = 0.f, xr1 = 0.f, xr2 = 0.f, xr3 = 0.f;
            float xr4 = 0.f, xr5 = 0.f, xr6 = 0.f, xr7 = 0.f;
            float xi0 = 0.f, xi1 = 0.f, xi2 = 0.f, xi3 = 0.f;
            float xi4 = 0.f, xi5 = 0.f, xi6 = 0.f, xi7 = 0.f;
#pragma unroll
            for (int i = 0; i < 9; ++i) {
                f32x4 lo = *(const f32x4*)(base + (size_t)i * MAT);
                f32x4 hi = *(const f32x4*)(base + (size_t)i * MAT + 4);
                float r = cR[i], m = cI[i];
                xr0 += r * lo[0]; xi0 += m * lo[0];
                xr1 += r * lo[1]; xi1 += m * lo[1];
                xr2 += r * lo[2]; xi2 += m * lo[2];
                xr3 += r * lo[3]; xi3 += m * lo[3];
                xr4 += r * hi[0]; xi4 += m * hi[0];
                xr5 += r * hi[1]; xi5 += m * hi[1];
                xr6 += r * hi[2]; xi6 += m * hi[2];
                xr7 += r * hi[3]; xi7 += m * hi[3];
            }
            bf16x8 vr, vi;
            vr[0] = (bf16)xr0; vr[1] = (bf16)xr1; vr[2] = (bf16)xr2; vr[3] = (bf16)xr3;
            vr[4] = (bf16)xr4; vr[5] = (bf16)xr5; vr[6] = (bf16)xr6; vr[7] = (bf16)xr7;
            vi[0] = (bf16)xi0; vi[1] = (bf16)xi1; vi[2] = (bf16)xi2; vi[3] = (bf16)xi3;
            vi[4] = (bf16)xi4; vi[5] = (bf16)xi5; vi[6] = (bf16)xi6; vi[7] = (bf16)xi7;
            int e = a * CH + swz8(c, a) * 8;      // swizzled (write side)
            *(i32x4*)&lds[e]       = __builtin_bit_cast(i32x4, vr);
            *(i32x4*)&lds[MAT + e] = __builtin_bit_cast(i32x4, vi);
        }
    }
    __syncthreads();

    // per-thread frag row constants
    int arow[3], abit[3], brow[3], bbit[3];
#pragma unroll
    for (int i = 0; i < 3; ++i) {
        int ra = rb + i * 16 + ml;
        arow[i] = ra * CH; abit[i] = ra & 7;
        int rc = cb + i * 16 + ml;
        brow[i] = rc * CH; bbit[i] = rc & 7;
    }

    f32x4 cr[3][3], ci[3][3];
#pragma unroll 1
    for (int round = 0; round < 3; ++round) {
        bool active = (round < 2) || (cb >= rb);    // round 3: upper triangle
#pragma unroll
        for (int i = 0; i < 3; ++i)
#pragma unroll
            for (int j = 0; j < 3; ++j) {
                cr[i][j] = f32x4{0.f, 0.f, 0.f, 0.f};
                ci[i][j] = f32x4{0.f, 0.f, 0.f, 0.f};
            }
        if (active) {
#pragma unroll
            for (int ks8 = 0; ks8 < 24; ks8 += 4) {     // K step 32 = 4 chunks
                int c0 = ks8 + kqc;
                bf16x8 ar[3], ai[3];
#pragma unroll
                for (int mt = 0; mt < 3; ++mt) {
                    int e = arow[mt] + swz8(c0, abit[mt]) * 8;
                    ar[mt] = *(const bf16x8*)&lds[e];
                    ai[mt] = *(const bf16x8*)&lds[MAT + e];
                }
#pragma unroll
                for (int nt = 0; nt < 3; ++nt) {
                    int e = brow[nt] + swz8(c0, bbit[nt]) * 8;
                    bf16x8 br = *(const bf16x8*)&lds[e];
                    bf16x8 bi = *(const bf16x8*)&lds[MAT + e];
                    i32x4 u = __builtin_bit_cast(i32x4, br);
                    u ^= 0x80008000;                    // nbr = -br (8 bf16)
                    bf16x8 nbr = __builtin_bit_cast(bf16x8, u);
                    __builtin_amdgcn_s_setprio(1);
#pragma unroll
                    for (int mt = 0; mt < 3; ++mt) {
                        // cr += ar*br + ai*bi ; ci += ar*bi + ai*(-br)
                        cr[mt][nt] = __builtin_amdgcn_mfma_f32_16x16x32_bf16(ar[mt], br,  cr[mt][nt], 0, 0, 0);
                        ci[mt][nt] = __builtin_amdgcn_mfma_f32_16x16x32_bf16(ar[mt], bi,  ci[mt][nt], 0, 0, 0);
                        cr[mt][nt] = __builtin_amdgcn_mfma_f32_16x16x32_bf16(ai[mt], bi,  cr[mt][nt], 0, 0, 0);
                        ci[mt][nt] = __builtin_amdgcn_mfma_f32_16x16x32_bf16(ai[mt], nbr, ci[mt][nt], 0, 0, 0);
                    }
                    __builtin_amdgcn_s_setprio(0);
                }
            }
        }
        if (round < 2) {
            __syncthreads();                        // all LDS reads done
            // transposed-packed write-back: store H^T (bitwise-Hermitian ->
            // transposes cancel across rounds; s3 unchanged). Lane's 4 rr
            // rows are 4 consecutive elems of stored column -> one b64.
            int lrq = kqc * 4;
#pragma unroll
            for (int mt = 0; mt < 3; ++mt) {
                int row0 = rb + mt * 16 + lrq;      // multiple of 4
                int rc = row0 >> 3, rlo = row0 & 7; // rlo in {0,4}
#pragma unroll
                for (int nt = 0; nt < 3; ++nt) {
                    int col = cb + nt * 16 + ml;
                    int e = col * CH + swz8(rc, col) * 8 + rlo;
                    bf16x4 pr, pi;
#pragma unroll
                    for (int rr = 0; rr < 4; ++rr) {
                        pr[rr] = (bf16)cr[mt][nt][rr];
                        pi[rr] = (bf16)ci[mt][nt][rr];
                    }
                    *(i32x2*)&lds[e]       = __builtin_bit_cast(i32x2, pr);
                    *(i32x2*)&lds[MAT + e] = __builtin_bit_cast(i32x2, pi);
                }
            }
            __syncthreads();                        // writes visible to round+1
        }
    }

    // ---- norm of round-3 accums: triangle, diag w=1, off-diag w=2 ----
    float loc = 0.f;
#pragma unroll
    for (int mt = 0; mt < 3; ++mt)
#pragma unroll
        for (int nt = 0; nt < 3; ++nt)
#pragma unroll
            for (int rr = 0; rr < 4; ++rr)
                loc += cr[mt][nt][rr] * cr[mt][nt][rr] + ci[mt][nt][rr] * ci[mt][nt][rr];
    float wt = (cb > rb) ? 2.0f : ((cb == rb) ? 1.0f : 0.0f);
    loc *= wt;
#pragma unroll
    for (int off = 32; off > 0; off >>= 1) loc += __shfl_down(loc, off, 64);
    if (lane == 0) red[w] = loc;
    __syncthreads();
    if (tid == 0) {
        float base = (f == 0) ? 1.0f : 2.0f;        // conj-pair weight over freqs
        float acc = 0.f;
#pragma unroll
        for (int i = 0; i < 16; ++i) acc += red[i];
        atomicAdd(s3, base * acc);
    }
}

// sigma = 1024 * (s3/289)^(1/16);  out = K / sigma
__global__ void k_scale(const float* __restrict__ K, float* __restrict__ out,
                        const float* __restrict__ s3) {
    float sig = 1024.0f * exp2f(log2f((*s3) * (1.0f / 289.0f)) * 0.0625f);
    float inv = 1.0f / sig;
    int i = (blockIdx.x * 256 + threadIdx.x) * 4;   // 324 blocks exact
    f32x4 v = *(const f32x4*)(K + i);
    v *= inv;
    *(f32x4*)(out + i) = v;
}

extern "C" void kernel_launch(void* const* d_in, const int* in_sizes, int n_in,
                              void* d_out, int out_size, void* d_ws, size_t ws_size,
                              hipStream_t stream) {
    const float* K = (const float*)d_in[0];
    float* out = (float*)d_out;
    char* ws = (char*)d_ws;
    float* s3 = (float*)ws;
    float* Kt = (float*)(ws + 256);

    k_tr<<<NELEM / (256 * 9), 256, 0, stream>>>(K, Kt, s3);   // 9-plane Kt + s3=0
    k_g3<<<NF, 1024, 0, stream>>>(Kt, s3);                    // DFT + 3 gram rounds
    k_scale<<<NELEM / 1024, 256, 0, stream>>>(K, out, s3);    // out = K/sigma
}

// Round 10
// 103.659 us; speedup vs baseline: 1.1997x; 1.0437x over previous
//
#include <hip/hip_runtime.h>
#include <hip/hip_bf16.h>

typedef __bf16 bf16;
typedef __attribute__((ext_vector_type(8))) __bf16 bf16x8;
typedef __attribute__((ext_vector_type(4))) __bf16 bf16x4;
typedef __attribute__((ext_vector_type(4))) float f32x4;
typedef __attribute__((ext_vector_type(4))) int i32x4;
typedef __attribute__((ext_vector_type(2))) int i32x2;

#define CH 192
#define MAT (CH * CH)            // 36864
#define NF 145                   // canonical frequencies of 17x17 grid (conj symmetry)
#define NELEM (CH * CH * 9)      // 331776
#define XSCALE 9.765625e-4f      // 2^-10, exact; sigma = 1024*(s3/289)^(1/16)
#define W17 0.36959913571644626f // 2*pi/17

// ---------------------------------------------------------------------------
// sigma = ||G^3(K)||_F^(1/8) via 17x17 spectral sampling (exact Parseval).
// ROUND-15: revert r9's Hermitian mirror (FAILED 1.22e-3: ci mirror is NOT
// bitwise -- the two half-sums S1=Re*Im', S2=-Im*Re' land in swapped order
// and f32 add is non-associative; only the cr mirror commutes exactly).
// Back to r8's full 16-tile rounds 1-2 (passed, 58us), keeping the two
// provably-bitwise-neutral r9 pieces:
//  - mt-major MFMA order: per-accumulator sequence unchanged (bitwise id),
//    dep distance 2 -> 6 MFMAs (kills accumulator-latency stalls).
//  - BALANCED round-3 triangle: r8's cb>=rb mask put {4,3,2,1} active waves
//    on SIMDs {3,2,1,0} -> critical SIMD did full work. Remap to 10-tile
//    triangle over waves 0-9 (per-SIMD active 3,3,2,2): critical 4 -> 3
//    units. Same values, same order, only wave->tile map changes (red[]
//    permutation ~1e-8 on s3; atomic order was already nondeterministic).
//  - swizzle row-bit == ml&7 uniformly (bands are multiples of 48 == 0 mod 8).
// Lessons pinned:
//  - ci Hermitian mirror NOT bitwise (r9, half-sum order swap). cr is.
//  - 16-wave block: ~64 arch VGPR + acc in unified file; any phase >64 live
//    arch VGPRs spills (r2-r6). Keep live sets small.
//  - Lane-adjacent addresses must be contiguous (r7 gather +22us).
//  - XOR chunk swizzle c'=(c&~7)|((c&7)^(r&7)) BOTH sides: conflicts 2M->0.
//  - FETCH ~14.5MB = Kt x8 XCDs; WRITE ~18.5MB = harness-fill dirty-L2
//    writeback, NOT scratch. Don't chase them.
//  - harness ws fill (~44 us) is inside the timed window: floor = 44 + work.
// ws layout: [0] float s3; [256] Kt f32 [i][a][o] 9 planes (1.33 MB).
// ---------------------------------------------------------------------------

__device__ __forceinline__ int swz8(int c, int r) {
    return (c & ~7) | ((c & 7) ^ (r & 7));       // 16-B chunk XOR swizzle
}

// Kt[i*MAT + a*CH + o] = K[(o*CH+a)*9 + i]; coalesced 36-B read per thread,
// 9 scattered scalar writes (fire-and-forget). Also zeroes s3.
__global__ void k_tr(const float* __restrict__ K, float* __restrict__ Kt,
                     float* __restrict__ s3) {
    int p = blockIdx.x * 256 + threadIdx.x;      // 144 blocks = 36864 rows
    if (p == 0) *s3 = 0.0f;
    int o = p / CH, a = p % CH;
    const float* src = K + (size_t)p * 9;
#pragma unroll
    for (int i = 0; i < 9; ++i)
        Kt[(size_t)i * MAT + a * CH + o] = src[i];
}

// ---------------------------------------------------------------------------
// k_g3: per-frequency fused DFT + triple gram. One block = one freq, 1024 thr.
// Staging: 9-plane coeff DFT, coalesced f32x4 plane reads -> swizzled LDS
// (Re/Im slabs [192][192] bf16, 147456 B). Rounds 1-2: full 16 tiles (wave w
// = rows (w>>2)*48, cols (w&3)*48); MFMA mt-major -> barrier -> transposed-
// packed b64 write-back -> barrier. Round 3: balanced 10-tile triangle
// (waves 0-9), norm of accums (off-diag x2) -> atomic.
// ---------------------------------------------------------------------------
__global__ __launch_bounds__(1024, 4)
__attribute__((amdgpu_waves_per_eu(4, 4)))
void k_g3(const float* __restrict__ Kt, float* __restrict__ s3) {
    __shared__ __align__(16) bf16 lds[2 * MAT];   // 147456 B
    __shared__ float twc[17], tws[17];
    __shared__ float red[16];
    int f = blockIdx.x;                 // 145 blocks
    int tid = threadIdx.x;
    int lane = tid & 63, w = tid >> 6;
    int ml = lane & 15, kqc = lane >> 4;
    int mlb = ml & 7;                   // swizzle row-bit for ALL frag rows
    int rb = (w >> 2) * 48;             // rounds 1-2: full 4x4 tiling
    int cb = (w & 3) * 48;
    // round-3 balanced triangle: waves 0-9 -> (0,0)(0,1)(0,2)(0,3)(1,1)
    // (1,2)(1,3)(2,2)(2,3)(3,3); per-SIMD active = 3,3,2,2
    int tr = (w >= 4) + (w >= 7) + (w >= 9);
    int tbase = (tr == 0) ? 0 : (tr == 1) ? 4 : (tr == 2) ? 7 : 9;
    int tc = w - tbase + tr;
    bool comp3 = (w < 10);
    bool offd3 = comp3 && (tc > tr);
    int rb3 = tr * 48, cb3 = tc * 48;

    if (tid < 17) {
        float s, c;
        __sincosf(-W17 * (float)tid, &s, &c);
        twc[tid] = c; tws[tid] = s;
    }
    __syncthreads();

    // ---- 9 block-uniform complex coeffs c[y*3+x] = py^y * px^x * 2^-10 ----
    int fy, fx;
    if (f < 9) { fy = 0; fx = f; }
    else { int uu = f - 9; fy = 1 + uu / 17; fx = uu % 17; }
    float pyr = twc[fy], pyi = tws[fy];
    float pxr = twc[fx], pxi = tws[fx];
    int fx2 = 2 * fx; if (fx2 >= 17) fx2 -= 17;
    int fy2 = 2 * fy; if (fy2 >= 17) fy2 -= 17;
    float px2r = twc[fx2], px2i = tws[fx2];
    float py2r = twc[fy2], py2i = tws[fy2];
    float cR[9], cI[9];
    cR[0] = 1.0f;  cI[0] = 0.0f;
    cR[1] = pxr;   cI[1] = pxi;
    cR[2] = px2r;  cI[2] = px2i;
    cR[3] = pyr;   cI[3] = pyi;
    cR[4] = pyr * pxr - pyi * pxi;    cI[4] = pyr * pxi + pyi * pxr;
    cR[5] = pyr * px2r - pyi * px2i;  cI[5] = pyr * px2i + pyi * px2r;
    cR[6] = py2r;  cI[6] = py2i;
    cR[7] = py2r * pxr - py2i * pxi;  cI[7] = py2r * pxi + py2i * pxr;
    cR[8] = py2r * px2r - py2i * px2i; cI[8] = py2r * px2i + py2i * px2r;
#pragma unroll
    for (int i = 0; i < 9; ++i) { cR[i] *= XSCALE; cI[i] *= XSCALE; }  // exact 2^-10

    // ---- stage: X_f = sum_i c_i * plane_i -> swizzled LDS (4608 chunks) ----
#pragma unroll 1
    for (int j5 = 0; j5 < 5; ++j5) {
        int cidx = j5 * 1024 + tid;
        if (cidx < 4608) {                        // last pass: waves 0-7 only
            int a = cidx / 24, c = cidx % 24;
            const float* base = Kt + a * CH + c * 8;
            float xr0 = 0.f, xr1 = 0.f, xr2 = 0.f, xr3 = 0.f;
            float xr4 = 0.f, xr5 = 0.f, xr6 = 0.f, xr7 = 0.f;
            float xi0 = 0.f, xi1 = 0.f, xi2 = 0.f, xi3 = 0.f;
            float xi4 = 0.f, xi5 = 0.f, xi6 = 0.f, xi7 = 0.f;
#pragma unroll
            for (int i = 0; i < 9; ++i) {
                f32x4 lo = *(const f32x4*)(base + (size_t)i * MAT);
                f32x4 hi = *(const f32x4*)(base + (size_t)i * MAT + 4);
                float r = cR[i], m = cI[i];
                xr0 += r * lo[0]; xi0 += m * lo[0];
                xr1 += r * lo[1]; xi1 += m * lo[1];
                xr2 += r * lo[2]; xi2 += m * lo[2];
                xr3 += r * lo[3]; xi3 += m * lo[3];
                xr4 += r * hi[0]; xi4 += m * hi[0];
                xr5 += r * hi[1]; xi5 += m * hi[1];
                xr6 += r * hi[2]; xi6 += m * hi[2];
                xr7 += r * hi[3]; xi7 += m * hi[3];
            }
            bf16x8 vr, vi;
            vr[0] = (bf16)xr0; vr[1] = (bf16)xr1; vr[2] = (bf16)xr2; vr[3] = (bf16)xr3;
            vr[4] = (bf16)xr4; vr[5] = (bf16)xr5; vr[6] = (bf16)xr6; vr[7] = (bf16)xr7;
            vi[0] = (bf16)xi0; vi[1] = (bf16)xi1; vi[2] = (bf16)xi2; vi[3] = (bf16)xi3;
            vi[4] = (bf16)xi4; vi[5] = (bf16)xi5; vi[6] = (bf16)xi6; vi[7] = (bf16)xi7;
            int e = a * CH + swz8(c, a) * 8;      // swizzled (write side)
            *(i32x4*)&lds[e]       = __builtin_bit_cast(i32x4, vr);
            *(i32x4*)&lds[MAT + e] = __builtin_bit_cast(i32x4, vi);
        }
    }
    __syncthreads();

    f32x4 cr[3][3], ci[3][3];
#pragma unroll 1
    for (int round = 0; round < 3; ++round) {
        bool last = (round == 2);
        int Rb = last ? rb3 : rb;
        int Cb = last ? cb3 : cb;
        bool active = !last || comp3;
#pragma unroll
        for (int i = 0; i < 3; ++i)
#pragma unroll
            for (int j = 0; j < 3; ++j) {
                cr[i][j] = f32x4{0.f, 0.f, 0.f, 0.f};
                ci[i][j] = f32x4{0.f, 0.f, 0.f, 0.f};
            }
        if (active) {
#pragma unroll
            for (int ks8 = 0; ks8 < 24; ks8 += 4) {     // K step 32 = 4 chunks
                int c0 = ks8 + kqc;
                int sw = swz8(c0, mlb) * 8;             // same for all frag rows
                bf16x8 ar[3], ai[3];
#pragma unroll
                for (int mt = 0; mt < 3; ++mt) {
                    int e = (Rb + mt * 16 + ml) * CH + sw;
                    ar[mt] = *(const bf16x8*)&lds[e];
                    ai[mt] = *(const bf16x8*)&lds[MAT + e];
                }
#pragma unroll
                for (int nt = 0; nt < 3; ++nt) {
                    int e = (Cb + nt * 16 + ml) * CH + sw;
                    bf16x8 br = *(const bf16x8*)&lds[e];
                    bf16x8 bi = *(const bf16x8*)&lds[MAT + e];
                    i32x4 u = __builtin_bit_cast(i32x4, br);
                    u ^= 0x80008000;                    // nbr = -br (8 bf16)
                    bf16x8 nbr = __builtin_bit_cast(bf16x8, u);
                    // mt-major: per-accumulator order unchanged (bitwise id
                    // vs r8); dep distance 2 -> 6
                    __builtin_amdgcn_s_setprio(1);
#pragma unroll
                    for (int mt = 0; mt < 3; ++mt)
                        cr[mt][nt] = __builtin_amdgcn_mfma_f32_16x16x32_bf16(ar[mt], br,  cr[mt][nt], 0, 0, 0);
#pragma unroll
                    for (int mt = 0; mt < 3; ++mt)
                        ci[mt][nt] = __builtin_amdgcn_mfma_f32_16x16x32_bf16(ar[mt], bi,  ci[mt][nt], 0, 0, 0);
#pragma unroll
                    for (int mt = 0; mt < 3; ++mt)
                        cr[mt][nt] = __builtin_amdgcn_mfma_f32_16x16x32_bf16(ai[mt], bi,  cr[mt][nt], 0, 0, 0);
#pragma unroll
                    for (int mt = 0; mt < 3; ++mt)
                        ci[mt][nt] = __builtin_amdgcn_mfma_f32_16x16x32_bf16(ai[mt], nbr, ci[mt][nt], 0, 0, 0);
                    __builtin_amdgcn_s_setprio(0);
                }
            }
        }
        if (!last) {
            __syncthreads();                        // all LDS reads done
            // transposed-packed write-back: store H^T (bitwise-Hermitian ->
            // transposes cancel across rounds; s3 unchanged). Lane's 4 rr
            // rows are 4 consecutive elems of stored column -> one b64.
            int lrq = kqc * 4;
#pragma unroll
            for (int mt = 0; mt < 3; ++mt) {
                int row0 = rb + mt * 16 + lrq;      // multiple of 4
                int rc = row0 >> 3, rlo = row0 & 7; // rlo in {0,4}
#pragma unroll
                for (int nt = 0; nt < 3; ++nt) {
                    int col = cb + nt * 16 + ml;
                    int e = col * CH + swz8(rc, mlb) * 8 + rlo;  // col&7 == mlb
                    bf16x4 pr, pi;
#pragma unroll
                    for (int rr = 0; rr < 4; ++rr) {
                        pr[rr] = (bf16)cr[mt][nt][rr];
                        pi[rr] = (bf16)ci[mt][nt][rr];
                    }
                    *(i32x2*)&lds[e]       = __builtin_bit_cast(i32x2, pr);
                    *(i32x2*)&lds[MAT + e] = __builtin_bit_cast(i32x2, pi);
                }
            }
            __syncthreads();                        // writes visible to round+1
        }
    }

    // ---- norm of round-3 accums: triangle, diag w=1, off-diag w=2 ----
    float loc = 0.f;
#pragma unroll
    for (int mt = 0; mt < 3; ++mt)
#pragma unroll
        for (int nt = 0; nt < 3; ++nt)
#pragma unroll
            for (int rr = 0; rr < 4; ++rr)
                loc += cr[mt][nt][rr] * cr[mt][nt][rr] + ci[mt][nt][rr] * ci[mt][nt][rr];
    loc *= offd3 ? 2.0f : (comp3 ? 1.0f : 0.0f);
#pragma unroll
    for (int off = 32; off > 0; off >>= 1) loc += __shfl_down(loc, off, 64);
    if (lane == 0) red[w] = loc;
    __syncthreads();
    if (tid == 0) {
        float base = (f == 0) ? 1.0f : 2.0f;        // conj-pair weight over freqs
        float acc = 0.f;
#pragma unroll
        for (int i = 0; i < 16; ++i) acc += red[i];
        atomicAdd(s3, base * acc);
    }
}

// sigma = 1024 * (s3/289)^(1/16);  out = K / sigma
__global__ void k_scale(const float* __restrict__ K, float* __restrict__ out,
                        const float* __restrict__ s3) {
    float sig = 1024.0f * exp2f(log2f((*s3) * (1.0f / 289.0f)) * 0.0625f);
    float inv = 1.0f / sig;
    int i = (blockIdx.x * 256 + threadIdx.x) * 4;   // 324 blocks exact
    f32x4 v = *(const f32x4*)(K + i);
    v *= inv;
    *(f32x4*)(out + i) = v;
}

extern "C" void kernel_launch(void* const* d_in, const int* in_sizes, int n_in,
                              void* d_out, int out_size, void* d_ws, size_t ws_size,
                              hipStream_t stream) {
    const float* K = (const float*)d_in[0];
    float* out = (float*)d_out;
    char* ws = (char*)d_ws;
    float* s3 = (float*)ws;
    float* Kt = (float*)(ws + 256);

    k_tr<<<NELEM / (256 * 9), 256, 0, stream>>>(K, Kt, s3);   // 9-plane Kt + s3=0
    k_g3<<<NF, 1024, 0, stream>>>(Kt, s3);                    // DFT + 3 gram rounds
    k_scale<<<NELEM / 1024, 256, 0, stream>>>(K, out, s3);    // out = K/sigma
}